// Round 7
// baseline (418.323 us; speedup 1.0000x reference)
//
#include <hip/hip_runtime.h>
#include <hip/hip_cooperative_groups.h>

namespace cg = cooperative_groups;

// Problem constants (fixed by the reference):
//   T = B*C = 4 trees, N = 262144 = 2^18 nodes/tree, HW = 1048576 = 2^20 pixels/tree
#define NT 4
#define NN 262144
#define NMASK (NN - 1)
#define HW 1048576
#define KPRE 4096    // prefix region solved in LDS (24KB -> 4 blocks/CU)

typedef int   vi4 __attribute__((ext_vector_type(4)));
typedef float vf4 __attribute__((ext_vector_type(4)));

// XCD-locality swizzle (perf heuristic): blocks dispatch round-robin across
// 8 XCDs; tree=(b&7)>>1 keeps each XCD's random-gather working set at one
// tree across ALL phases (cmb 2MB + v 1MB + levels 1MB < 4MB L2).
// chunk in [0,256) for 1024 blocks.
#define SWIZ(b, tree, chunk)                \
    int tree  = ((b) & 7) >> 1;             \
    int chunk = (((b) >> 3) << 1) | ((b) & 1);

// ---------------------------------------------------------------------------
// One cooperative persistent kernel, three phases, two grid syncs.
// Eliminates 3 kernel-dispatch boundaries (launch gaps + per-boundary L2
// coherence flushes) of the 4-kernel pipeline.
//
//  Phase 1 (concurrent):
//   - chunks 0..251:  build cmb[i]={parent,c} for nodes [KPRE,NN):
//       c[i] = sigmoid(clip(1000*(attr-thr),-12,12)) * (levels[i]-levels[par])
//   - chunk 255 (one block per tree): solve v[0..KPRE) entirely in LDS.
//  Phase 2: chunks 0..251: chain walk for nodes [KPRE,NN): descend (~4.2 avg
//           steps) until index < KPRE, fold in prefix v, write v coalesced.
//  Phase 3: all chunks: pixel gather y[t][p] = v[t][p2n[t][p]], vectorized.
// ---------------------------------------------------------------------------
__global__ __launch_bounds__(256, 4) void k_fused(const float* __restrict__ attr,
                                                  const float* __restrict__ levels,
                                                  const float* __restrict__ thr,
                                                  const int* __restrict__ parent,
                                                  const int* __restrict__ p2n,
                                                  float* __restrict__ y,
                                                  int2* __restrict__ cmb,
                                                  float* __restrict__ v) {
    __shared__ float lvcs[KPRE];             // 16KB: levels, then c
    __shared__ unsigned short ps[KPRE];      // 8KB: parents (all < KPRE)

    cg::grid_group grid = cg::this_grid();
    int b = blockIdx.x;
    SWIZ(b, tree, chunk)
    int tbase = tree << 18;
    int tid = threadIdx.x;
    float t0 = thr[0];

    // ---------------- Phase 1 ----------------
    if (chunk < 252) {
        // build: one int4-granule per thread
        int idx4 = KPRE / 4 + chunk * 256 + tid;
        vi4 p4 = ((const vi4*)(parent + tbase))[idx4];
        vf4 a4 = ((const vf4*)(attr + tbase))[idx4];
        vf4 l4 = ((const vf4*)(levels + tbase))[idx4];
        int oc[8];
#pragma unroll
        for (int e = 0; e < 4; ++e) {
            int p = p4[e] & NMASK;
            float lp = levels[tbase + p];    // tree-local random gather
            float z = 1000.0f * (a4[e] - t0);
            z = fminf(fmaxf(z, -12.0f), 12.0f);
            float s = 1.0f / (1.0f + __expf(-z));
            oc[2 * e] = p;
            oc[2 * e + 1] = __float_as_int(s * (l4[e] - lp));
        }
        vi4* dst = (vi4*)(cmb + tbase);
        dst[2 * idx4]     = (vi4){oc[0], oc[1], oc[2], oc[3]};
        dst[2 * idx4 + 1] = (vi4){oc[4], oc[5], oc[6], oc[7]};
    } else if (chunk == 255) {
        // prefix solve for this tree, fully in LDS
        for (int j = tid; j < KPRE; j += 256) {
            lvcs[j] = levels[tbase + j];
            ps[j] = (unsigned short)(parent[tbase + j] & (KPRE - 1));
        }
        __syncthreads();
        float creg[16];
#pragma unroll
        for (int k = 0; k < 16; ++k) {
            int j = tid + k * 256;
            float lv = lvcs[j];
            float lp = lvcs[ps[j]];
            float z = 1000.0f * (attr[tbase + j] - t0);
            z = fminf(fmaxf(z, -12.0f), 12.0f);
            float s = 1.0f / (1.0f + __expf(-z));
            creg[k] = (j == 0) ? lv : s * (lv - lp);
        }
        __syncthreads();
#pragma unroll
        for (int k = 0; k < 16; ++k) lvcs[tid + k * 256] = creg[k];
        __syncthreads();

        int   cur[16];
        float acc[16];
        int alive = 0xFFFF;
#pragma unroll
        for (int k = 0; k < 16; ++k) { cur[k] = tid + k * 256; acc[k] = 0.0f; }
        // max depth of random recursive tree @4096 ~ e*ln(4096) ~ 23; 64 = guard
        for (int it = 0; it < 64 && __any(alive); ++it) {
#pragma unroll
            for (int k = 0; k < 16; ++k) {
                if (alive & (1 << k)) {
                    int c_ = cur[k];
                    acc[k] += lvcs[c_];          // c[0]=levels[0] at root
                    if (c_ == 0) alive &= ~(1 << k);
                    else cur[k] = ps[c_];
                }
            }
        }
#pragma unroll
        for (int k = 0; k < 16; ++k)
            v[tbase + tid + k * 256] = acc[k];
    }

    grid.sync();

    // ---------------- Phase 2: walk ----------------
    if (chunk < 252) {
        int base = KPRE + chunk * 1024;
        const int2*  ct = cmb + tbase;
        const float* vt = v + tbase;
        int   cur[4];
        float acc[4];
        int alive = 0xF;
#pragma unroll
        for (int k = 0; k < 4; ++k) { cur[k] = base + tid + k * 256; acc[k] = 0.0f; }
        for (int it = 0; it < 64 && __any(alive); ++it) {
#pragma unroll
            for (int k = 0; k < 4; ++k) {
                if (alive & (1 << k)) {
                    int2 rec = ct[cur[k]];   // one 8B gather per step, tree-local
                    acc[k] += __int_as_float(rec.y);
                    int nxt = rec.x;
                    if (nxt < KPRE) {        // terminate: fold in prefix value
                        acc[k] += vt[nxt];   // 16KB region -> L1-hot
                        alive &= ~(1 << k);
                    } else {
                        cur[k] = nxt;
                    }
                }
            }
        }
#pragma unroll
        for (int k = 0; k < 4; ++k)
            v[tbase + base + tid + k * 256] = acc[k];   // coalesced
    }

    grid.sync();

    // ---------------- Phase 3: pixel gather ----------------
    {
        const float* vt = v + tbase;
        const vi4* p2n4 = (const vi4*)p2n;
        vf4* y4 = (vf4*)y;
#pragma unroll
        for (int k = 0; k < 4; ++k) {
            int i4 = tbase + chunk * 1024 + k * 256 + tid;  // int4 index
            vi4 idx = p2n4[i4];
            vf4 o;
            o.x = vt[idx.x & NMASK];
            o.y = vt[idx.y & NMASK];
            o.z = vt[idx.z & NMASK];
            o.w = vt[idx.w & NMASK];
            y4[i4] = o;
        }
    }
}

extern "C" void kernel_launch(void* const* d_in, const int* in_sizes, int n_in,
                              void* d_out, int out_size, void* d_ws, size_t ws_size,
                              hipStream_t stream) {
    // inputs: 0:x (unused), 1:attr_norm, 2:levels, 3:thr, 4:parent, 5:pixel_to_node
    const float* attr   = (const float*)d_in[1];
    const float* levels = (const float*)d_in[2];
    const float* thr    = (const float*)d_in[3];
    const int*   parent = (const int*)d_in[4];
    const int*   p2n    = (const int*)d_in[5];
    float*       y      = (float*)d_out;

    int2*  cmb = (int2*)d_ws;                                  // 8 MB
    float* v   = (float*)((char*)d_ws + (size_t)NT * NN * 8);  // 4 MB

    void* args[] = {(void*)&attr, (void*)&levels, (void*)&thr, (void*)&parent,
                    (void*)&p2n, (void*)&y, (void*)&cmb, (void*)&v};
    hipLaunchCooperativeKernel((void*)k_fused, dim3(1024), dim3(256), args, 0, stream);
}